// Round 10
// baseline (18711.465 us; speedup 1.0000x reference)
//
#include <hip/hip_runtime.h>
#include <cstdint>
#include <cstddef>

typedef unsigned short u16;
typedef unsigned int u32;
typedef unsigned long long u64;
typedef __attribute__((ext_vector_type(8))) short bfrag8;   // 8 bf16 = 4 VGPRs
typedef __attribute__((ext_vector_type(4))) float f32x4;

#define NB 64      // batch
#define NT 512     // timesteps
#define NE 256     // embedding dim
#define NH 512     // hidden dim
#define NWG 128    // compute workgroups (4 units x 4 gates = 16 cols each)

__device__ __forceinline__ float bf2f(u16 b) { return __uint_as_float(((unsigned)b) << 16); }
__device__ __forceinline__ u16 f2bf(float f) {
  unsigned u = __float_as_uint(f);
  u += 0x7fffu + ((u >> 16) & 1u);   // round-to-nearest-even
  return (u16)(u >> 16);
}
__device__ __forceinline__ float fsigm(float x) { return 1.0f / (1.0f + __expf(-x)); }
__device__ __forceinline__ float ftanh(float x) { return 2.0f / (1.0f + __expf(-2.0f * x)) - 1.0f; }

// split fp32 -> (hi, lo) bf16 pair; hi + lo == v to ~2^-18 relative
__device__ __forceinline__ void split1(float v, u16& h, u16& l) {
  h = f2bf(v);
  float r = v - bf2f(h);
  l = f2bf(r);
}
__device__ __forceinline__ void split8(const float* p, bfrag8& hi, bfrag8& lo) {
#pragma unroll
  for (int i = 0; i < 8; ++i) {
    u16 h, l; split1(p[i], h, l);
    hi[i] = (short)h; lo[i] = (short)l;
  }
}

__device__ __forceinline__ void unpack8(uint4 q, float* o) {
  o[0] = __uint_as_float(q.x << 16); o[1] = __uint_as_float(q.x & 0xffff0000u);
  o[2] = __uint_as_float(q.y << 16); o[3] = __uint_as_float(q.y & 0xffff0000u);
  o[4] = __uint_as_float(q.z << 16); o[5] = __uint_as_float(q.z & 0xffff0000u);
  o[6] = __uint_as_float(q.w << 16); o[7] = __uint_as_float(q.w & 0xffff0000u);
}

// ---------------- persistent LSTM, tag-synchronized, FULL hi/lo h feedback ----
// WG g owns units [g*4,g*4+4) x 4 gates = 16 cols; wave w owns batch tile
// [16w,16w+16): self-contained 16x16 D-tile, no intra-loop barriers/fences.
// h exchange: hbuf[2][B][H] of u64 = (step_tag<<32)|(hi<<16)|lo  (ONE unit per
// u64: tag + fp32-equivalent hi/lo payload -- R9's hi-only feedback lost the
// recurrence at 1.1e-1; R5-R8 proved hi/lo gives 9.77e-4).
//   producer : ONE relaxed agent-scope u64 store per thread (its (b,u) unit).
//   consumer : 128 relaxed agent-scope u64 loads split in two 64-load halves
//              (VGPR budget: 128 live hq regs/half + 192 weight regs < 450
//              no-spill line), tag==t-1 check + retry per half.
// Skew safety (R9 argument, unchanged): tag t+1 stores require having read all
// tag-t values, which exist only after every WG read tag-(t-1) => parity-2
// buffer never overwritten early. 8B atomics => no torn values. Workspace
// poison 0xAAAAAAAA never matches tags 1..512 => no memset needed.
__global__ __launch_bounds__(256, 1) void lstm_persistent(
    const int* __restrict__ words,
    const float* __restrict__ emb,
    const float* __restrict__ Whr, const float* __restrict__ Whf,
    const float* __restrict__ Whg, const float* __restrict__ Who,
    const float* __restrict__ Wir, const float* __restrict__ Wif,
    const float* __restrict__ Wig, const float* __restrict__ Wio,
    const float* __restrict__ bhr, const float* __restrict__ bhf,
    const float* __restrict__ bhg, const float* __restrict__ bho,
    const float* __restrict__ bir, const float* __restrict__ bif,
    const float* __restrict__ big_, const float* __restrict__ bio,
    u64* __restrict__ hbuf,     // [2][B][H] tagged hi/lo units
    u16* __restrict__ hs_all,   // [T][B][H] bf16 (attention path)
    float* __restrict__ hlast)  // [B][H] fp32 final h
{
  const int wg = blockIdx.x;
  const int tid = threadIdx.x;
  const int lane = tid & 63;
  const int wave = tid >> 6;
  const int mbase = wave * 16;
  const int colq = lane & 15;
  const int koff = (lane >> 4) * 8;
  const int arow = mbase + colq;            // batch row for A fragments

  __shared__ float gatesLds[NB * 17];       // [b][col], stride 17; per-wave rows
  __shared__ float biasSum[16];

  if (tid < 16) {
    int gate = tid >> 2, u = tid & 3, gu = wg * 4 + u;
    const float* bh = (gate == 0) ? bhr : (gate == 1) ? bhf : (gate == 2) ? bhg : bho;
    const float* bi = (gate == 0) ? bir : (gate == 1) ? bif : (gate == 2) ? big_ : bio;
    biasSum[tid] = bh[gu] + bi[gu];
  }

  // ---- persistent weight fragments (hi/lo split), B-layout:
  // lane L holds B[k=(L>>4)*8+j][col=L&15]
  bfrag8 whh[16], whl[16], wih[8], wil[8];
  {
    int gate = colq >> 2;
    int gu = wg * 4 + (colq & 3);
    const float* wh = (gate == 0) ? Whr : (gate == 1) ? Whf : (gate == 2) ? Whg : Who;
    const float* wi = (gate == 0) ? Wir : (gate == 1) ? Wif : (gate == 2) ? Wig : Wio;
    const float* whp = wh + (size_t)gu * NH + koff;
    const float* wip = wi + (size_t)gu * NE + koff;
#pragma unroll
    for (int kt = 0; kt < 16; ++kt) split8(whp + kt * 32, whh[kt], whl[kt]);
#pragma unroll
    for (int kt = 0; kt < 8; ++kt)  split8(wip + kt * 32, wil[kt], wil[kt]), split8(wip + kt * 32, wih[kt], wil[kt]);
  }
  __syncthreads();   // ONLY barrier: biasSum init visibility

  // int64-vs-int32 hedge for word indices
  bool is64 = ((words[1] | words[3] | words[5] | words[7]) == 0);
  const int wstep = is64 ? 2 : 1;
  const int* wrow = words + (size_t)(is64 ? 2 : 1) * arow * NT;

  float cst = 0.0f;   // fp32 cell state for (b = tid>>2, u = tid&3)

  // ---- X pipeline: prologue loads + split for t=1 ----
  f32x4 nxa[8], nxb[8];        // raw fp32 emb for NEXT step (prefetch)
  bfrag8 xh[8], xl[8];         // split fragments for CURRENT step
  {
    int w0 = wrow[0];
    const float* xs = emb + (size_t)w0 * NE + koff;
#pragma unroll
    for (int kt = 0; kt < 8; ++kt) {
      nxa[kt] = *(const f32x4*)(xs + kt * 32);
      nxb[kt] = *(const f32x4*)(xs + kt * 32 + 4);
    }
#pragma unroll
    for (int kt = 0; kt < 8; ++kt) {
#pragma unroll
      for (int i = 0; i < 4; ++i) {
        u16 h, l;
        split1(nxa[kt][i], h, l); xh[kt][i] = (short)h; xl[kt][i] = (short)l;
        split1(nxb[kt][i], h, l); xh[kt][4 + i] = (short)h; xl[kt][4 + i] = (short)l;
      }
    }
  }

  for (int t = 1; t <= NT; ++t) {
    const u32 need = (u32)(t - 1);
    const u64* hp = hbuf + ((size_t)((t - 1) & 1) * NB + arow) * NH + koff;

    // ---- issue half-0 tagged h loads FIRST (RT overlaps x-MFMAs) ----
    u64 hq[8][8];
    if (t > 1) {
#pragma unroll
      for (int kt = 0; kt < 8; ++kt)
#pragma unroll
        for (int j = 0; j < 8; ++j)
          hq[kt][j] = __hip_atomic_load(hp + kt * 32 + j,
                                        __ATOMIC_RELAXED, __HIP_MEMORY_SCOPE_AGENT);
    }

    // ---- X MFMAs (independent of h_{t-1}) ----
    f32x4 acc = {0.f, 0.f, 0.f, 0.f};
#pragma unroll
    for (int kt = 0; kt < 8; ++kt) {
      acc = __builtin_amdgcn_mfma_f32_16x16x32_bf16(xh[kt], wih[kt], acc, 0, 0, 0);
      acc = __builtin_amdgcn_mfma_f32_16x16x32_bf16(xl[kt], wih[kt], acc, 0, 0, 0);
      acc = __builtin_amdgcn_mfma_f32_16x16x32_bf16(xh[kt], wil[kt], acc, 0, 0, 0);
    }

    if (t > 1) {
      // ---- half 0: tag check / retry, then MFMA ----
      for (;;) {
        bool ok = true;
#pragma unroll
        for (int kt = 0; kt < 8; ++kt)
#pragma unroll
          for (int j = 0; j < 8; ++j)
            ok &= ((u32)(hq[kt][j] >> 32) == need);
        if (__all(ok)) break;
        __builtin_amdgcn_s_sleep(1);
#pragma unroll
        for (int kt = 0; kt < 8; ++kt)
#pragma unroll
          for (int j = 0; j < 8; ++j)
            hq[kt][j] = __hip_atomic_load(hp + kt * 32 + j,
                                          __ATOMIC_RELAXED, __HIP_MEMORY_SCOPE_AGENT);
      }
#pragma unroll
      for (int kt = 0; kt < 8; ++kt) {
        bfrag8 ah, al;
#pragma unroll
        for (int j = 0; j < 8; ++j) {
          u32 lo32 = (u32)hq[kt][j];
          ah[j] = (short)(lo32 >> 16);
          al[j] = (short)(lo32 & 0xffffu);
        }
        acc = __builtin_amdgcn_mfma_f32_16x16x32_bf16(ah, whh[kt], acc, 0, 0, 0);
        acc = __builtin_amdgcn_mfma_f32_16x16x32_bf16(al, whh[kt], acc, 0, 0, 0);
        acc = __builtin_amdgcn_mfma_f32_16x16x32_bf16(ah, whl[kt], acc, 0, 0, 0);
      }

      // ---- half 1: load, tag check / retry, MFMA ----
#pragma unroll
      for (int kt = 0; kt < 8; ++kt)
#pragma unroll
        for (int j = 0; j < 8; ++j)
          hq[kt][j] = __hip_atomic_load(hp + (kt + 8) * 32 + j,
                                        __ATOMIC_RELAXED, __HIP_MEMORY_SCOPE_AGENT);
      for (;;) {
        bool ok = true;
#pragma unroll
        for (int kt = 0; kt < 8; ++kt)
#pragma unroll
          for (int j = 0; j < 8; ++j)
            ok &= ((u32)(hq[kt][j] >> 32) == need);
        if (__all(ok)) break;
        __builtin_amdgcn_s_sleep(1);
#pragma unroll
        for (int kt = 0; kt < 8; ++kt)
#pragma unroll
          for (int j = 0; j < 8; ++j)
            hq[kt][j] = __hip_atomic_load(hp + (kt + 8) * 32 + j,
                                          __ATOMIC_RELAXED, __HIP_MEMORY_SCOPE_AGENT);
      }
#pragma unroll
      for (int kt = 0; kt < 8; ++kt) {
        bfrag8 ah, al;
#pragma unroll
        for (int j = 0; j < 8; ++j) {
          u32 lo32 = (u32)hq[kt][j];
          ah[j] = (short)(lo32 >> 16);
          al[j] = (short)(lo32 & 0xffffu);
        }
        acc = __builtin_amdgcn_mfma_f32_16x16x32_bf16(ah, whh[kt + 8], acc, 0, 0, 0);
        acc = __builtin_amdgcn_mfma_f32_16x16x32_bf16(al, whh[kt + 8], acc, 0, 0, 0);
        acc = __builtin_amdgcn_mfma_f32_16x16x32_bf16(ah, whl[kt + 8], acc, 0, 0, 0);
      }
    }

    // ---- emb prefetch for t+1 (RT overlaps gate math + stores) ----
    if (t < NT) {
      int wn = wrow[(size_t)t * wstep];
      const float* xs = emb + (size_t)wn * NE + koff;
#pragma unroll
      for (int kt = 0; kt < 8; ++kt) {
        nxa[kt] = *(const f32x4*)(xs + kt * 32);
        nxb[kt] = *(const f32x4*)(xs + kt * 32 + 4);
      }
    }

    // ---- intra-wave transpose via LDS (wave's own rows; no barrier) ----
    {
      int drow = mbase + ((lane >> 4) << 2);
#pragma unroll
      for (int r = 0; r < 4; ++r) gatesLds[(drow + r) * 17 + colq] = acc[r];
    }

    // ---- elementwise gate math; thread owns one (b,u) (own wave's rows) ----
    float hv;
    int b, u;
    {
      b = tid >> 2; u = tid & 3;
      const float* gl = &gatesLds[b * 17];
      float xr = gl[u]      + biasSum[u];
      float xf = gl[4 + u]  + biasSum[4 + u];
      float xg = gl[8 + u]  + biasSum[8 + u];
      float xo = gl[12 + u] + biasSum[12 + u];
      float rg = fsigm(xr), fg = fsigm(xf), gg = ftanh(xg), og = fsigm(xo);
      cst = fg * cst + rg * gg;
      hv = og * ftanh(cst);
    }

    // ---- tagged store: one u64 per thread = (t<<32)|(hi<<16)|lo ----
    {
      u16 hhi, hlo; split1(hv, hhi, hlo);
      u64 q = ((u64)(u32)t << 32) | ((u32)hhi << 16) | (u32)hlo;
      __hip_atomic_store(&hbuf[((size_t)(t & 1) * NB + b) * NH + wg * 4 + u],
                         q, __ATOMIC_RELAXED, __HIP_MEMORY_SCOPE_AGENT);
      // off-critical-path history/final stores
      hs_all[(size_t)(t - 1) * (NB * NH) + b * NH + wg * 4 + u] = hhi;
      if (t == NT) hlast[b * NH + wg * 4 + u] = hv;
    }

    // ---- split prefetched X(t+1) -> fragments for next iteration ----
    if (t < NT) {
#pragma unroll
      for (int kt = 0; kt < 8; ++kt) {
#pragma unroll
        for (int i = 0; i < 4; ++i) {
          u16 h, l;
          split1(nxa[kt][i], h, l); xh[kt][i] = (short)h; xl[kt][i] = (short)l;
          split1(nxb[kt][i], h, l); xh[kt][4 + i] = (short)h; xl[kt][4 + i] = (short)l;
        }
      }
    }
  }
}

// ---------------- attention + output head (one WG per batch) ----------------
__global__ __launch_bounds__(256) void post_kernel(
    const float* __restrict__ hlast,  // [B][H] fp32
    const u16* __restrict__ hs,       // [T][B][H] bf16
    const float* __restrict__ W_ol, const float* __restrict__ b_ol,   // [256][512], [256]
    const float* __restrict__ W_att, const float* __restrict__ b_att, // [256][512], [512]
    const float* __restrict__ W_fc, const float* __restrict__ b_fc,   // [2][768], [2]
    float* __restrict__ out)          // [64*2] ++ [64*512] fp32
{
  int b = blockIdx.x, tid = threadIdx.x;
  __shared__ float hl[NH], fh[256], sc[NH], att[NT], ao[NH], red[256];

  for (int i = tid; i < NH; i += 256) {
    float hv = hlast[b * NH + i];
    hl[i] = hv;
    out[128 + b * NH + i] = hv;   // output 1: h_last
  }
  __syncthreads();

  // final_hidden[j] = b_ol[j] + hl . W_ol[j][:]
  {
    float s = b_ol[tid];
    const float* w = W_ol + (size_t)tid * NH;
    for (int k = 0; k < NH; k += 4) {
      f32x4 q = *(const f32x4*)(w + k);
      s += q[0] * hl[k] + q[1] * hl[k + 1] + q[2] * hl[k + 2] + q[3] * hl[k + 3];
    }
    fh[tid] = s;
  }
  __syncthreads();

  // score[h] = b_att[h] + sum_j fh[j] * W_att[j][h]
  for (int h = tid; h < NH; h += 256) {
    float s = b_att[h];
    for (int j = 0; j < 256; ++j) s += fh[j] * W_att[(size_t)j * NH + h];
    sc[h] = s;
  }
  __syncthreads();

  // att[t] = score . hs[t][b][:]
  for (int t = tid; t < NT; t += 256) {
    const u16* row = hs + ((size_t)t * NB + b) * NH;
    float s = 0.f;
    for (int k = 0; k < NH; k += 8) {
      uint4 q = *(const uint4*)(row + k);
      float tmp[8]; unpack8(q, tmp);
#pragma unroll
      for (int j = 0; j < 8; ++j) s += tmp[j] * sc[k + j];
    }
    att[t] = s;
  }
  __syncthreads();

  // softmax over T
  float l0 = att[tid], l1 = att[tid + 256];
  red[tid] = fmaxf(l0, l1);
  __syncthreads();
  for (int s = 128; s > 0; s >>= 1) { if (tid < s) red[tid] = fmaxf(red[tid], red[tid + s]); __syncthreads(); }
  float mx = red[0];
  __syncthreads();
  float e0 = __expf(l0 - mx), e1 = __expf(l1 - mx);
  red[tid] = e0 + e1;
  __syncthreads();
  for (int s = 128; s > 0; s >>= 1) { if (tid < s) red[tid] += red[tid + s]; __syncthreads(); }
  float inv = 1.0f / red[0];
  __syncthreads();
  att[tid] = e0 * inv;
  att[tid + 256] = e1 * inv;
  __syncthreads();

  // att_out[h] = sum_t dist[t] * hs[t][b][h]
  {
    float a0 = 0.f, a1 = 0.f;
    for (int t = 0; t < NT; ++t) {
      float d = att[t];
      const u16* row = hs + ((size_t)t * NB + b) * NH;
      a0 += d * bf2f(row[tid]);
      a1 += d * bf2f(row[tid + 256]);
    }
    ao[tid] = a0;
    ao[tid + 256] = a1;
  }
  __syncthreads();

  // out[o] = sigmoid(b_fc[o] + [fh, ao] . W_fc[o][:])
#pragma unroll
  for (int o = 0; o < 2; ++o) {
    float part = 0.f;
    for (int i = tid; i < 768; i += 256) {
      float v = (i < 256) ? fh[i] : ao[i - 256];
      part += v * W_fc[o * 768 + i];
    }
    red[tid] = part;
    __syncthreads();
    for (int s = 128; s > 0; s >>= 1) { if (tid < s) red[tid] += red[tid + s]; __syncthreads(); }
    if (tid == 0) out[b * 2 + o] = fsigm(red[0] + b_fc[o]);
    __syncthreads();
  }
}

// ---------------- host launch ----------------
extern "C" void kernel_launch(void* const* d_in, const int* in_sizes, int n_in,
                              void* d_out, int out_size, void* d_ws, size_t ws_size,
                              hipStream_t stream) {
  const int* words  = (const int*)d_in[0];
  const float* emb  = (const float*)d_in[1];
  const float* Wir  = (const float*)d_in[2];  const float* bir = (const float*)d_in[3];
  const float* Whr  = (const float*)d_in[4];  const float* bhr = (const float*)d_in[5];
  const float* Wif  = (const float*)d_in[6];  const float* bif = (const float*)d_in[7];
  const float* Whf  = (const float*)d_in[8];  const float* bhf = (const float*)d_in[9];
  const float* Wig  = (const float*)d_in[10]; const float* big_ = (const float*)d_in[11];
  const float* Whg  = (const float*)d_in[12]; const float* bhg = (const float*)d_in[13];
  const float* Wio  = (const float*)d_in[14]; const float* bio = (const float*)d_in[15];
  const float* Who  = (const float*)d_in[16]; const float* bho = (const float*)d_in[17];
  const float* W_att = (const float*)d_in[18]; const float* b_att = (const float*)d_in[19];
  const float* W_ol  = (const float*)d_in[20]; const float* b_ol  = (const float*)d_in[21];
  const float* W_fc  = (const float*)d_in[22]; const float* b_fc  = (const float*)d_in[23];

  uint8_t* ws = (uint8_t*)d_ws;
  u16* hs       = (u16*)ws;                            // 512*64*512*2 = 32 MiB
  size_t off    = (size_t)33554432;
  u64* hbuf     = (u64*)(ws + off);  off += 524288;    // 2*64*512*8 tagged units
  float* hlast  = (float*)(ws + off);                  // 64*512*4 = 128 KiB

  // no flags / no memset: workspace poison tag 0xAAAAAAAA never matches 1..512

  lstm_persistent<<<dim3(NWG), dim3(256), 0, stream>>>(
      words, emb,
      Whr, Whf, Whg, Who,
      Wir, Wif, Wig, Wio,
      bhr, bhf, bhg, bho,
      bir, bif, big_, bio,
      hbuf, hs, hlast);

  post_kernel<<<dim3(NB), dim3(256), 0, stream>>>(hlast, hs, W_ol, b_ol, W_att, b_att,
                                                  W_fc, b_fc, (float*)d_out);
}

// Round 11
// 7290.326 us; speedup vs baseline: 2.5666x; 2.5666x over previous
//
#include <hip/hip_runtime.h>
#include <cstdint>
#include <cstddef>

typedef unsigned short u16;
typedef unsigned int u32;
typedef __attribute__((ext_vector_type(8))) short bfrag8;   // 8 bf16 = 4 VGPRs
typedef __attribute__((ext_vector_type(4))) float f32x4;

#define NB 64      // batch
#define NT 512     // timesteps
#define NE 256     // embedding dim
#define NH 512     // hidden dim
#define NWG 128    // compute workgroups (4 units x 4 gates = 16 cols each)

__device__ __forceinline__ float bf2f(u16 b) { return __uint_as_float(((unsigned)b) << 16); }
__device__ __forceinline__ u16 f2bf(float f) {
  unsigned u = __float_as_uint(f);
  u += 0x7fffu + ((u >> 16) & 1u);   // round-to-nearest-even
  return (u16)(u >> 16);
}
__device__ __forceinline__ float fsigm(float x) { return 1.0f / (1.0f + __expf(-x)); }
__device__ __forceinline__ float ftanh(float x) { return 2.0f / (1.0f + __expf(-2.0f * x)) - 1.0f; }

// split fp32 -> (hi, lo) bf16 pair; hi + lo == v to ~2^-18 relative
__device__ __forceinline__ void split1(float v, u16& h, u16& l) {
  h = f2bf(v);
  float r = v - bf2f(h);
  l = f2bf(r);
}
__device__ __forceinline__ void split8(const float* p, bfrag8& hi, bfrag8& lo) {
#pragma unroll
  for (int i = 0; i < 8; ++i) {
    u16 h, l; split1(p[i], h, l);
    hi[i] = (short)h; lo[i] = (short)l;
  }
}

__device__ __forceinline__ void unpack8(uint4 q, float* o) {
  o[0] = __uint_as_float(q.x << 16); o[1] = __uint_as_float(q.x & 0xffff0000u);
  o[2] = __uint_as_float(q.y << 16); o[3] = __uint_as_float(q.y & 0xffff0000u);
  o[4] = __uint_as_float(q.z << 16); o[5] = __uint_as_float(q.z & 0xffff0000u);
  o[6] = __uint_as_float(q.w << 16); o[7] = __uint_as_float(q.w & 0xffff0000u);
}

// ---------------- prologue: pre-split weights into per-lane fragment layout ----
// wbuf[wg][lane][48] bfrag8: [0..15]=Wh hi, [16..31]=Wh lo, [32..39]=Wi hi,
// [40..47]=Wi lo -- exactly the order lstm_step's lane (colq=lane&15,
// koff=(lane>>4)*8) consumes. bias_s[wg][16] = bh+bi fused.
__global__ __launch_bounds__(64) void stage_weights(
    const float* __restrict__ Whr, const float* __restrict__ Whf,
    const float* __restrict__ Whg, const float* __restrict__ Who,
    const float* __restrict__ Wir, const float* __restrict__ Wif,
    const float* __restrict__ Wig, const float* __restrict__ Wio,
    const float* __restrict__ bhr, const float* __restrict__ bhf,
    const float* __restrict__ bhg, const float* __restrict__ bho,
    const float* __restrict__ bir, const float* __restrict__ bif,
    const float* __restrict__ big_, const float* __restrict__ bio,
    u16* __restrict__ wbuf, float* __restrict__ bias_s)
{
  const int wg = blockIdx.x;
  const int lane = threadIdx.x;
  const int colq = lane & 15;
  const int koff = (lane >> 4) * 8;
  const int gate = colq >> 2;
  const int gu = wg * 4 + (colq & 3);
  const float* wh = (gate == 0) ? Whr : (gate == 1) ? Whf : (gate == 2) ? Whg : Who;
  const float* wi = (gate == 0) ? Wir : (gate == 1) ? Wif : (gate == 2) ? Wig : Wio;
  u16* wb = wbuf + (size_t)(wg * 64 + lane) * 48 * 8;
  const float* whp = wh + (size_t)gu * NH + koff;
  const float* wip = wi + (size_t)gu * NE + koff;
#pragma unroll
  for (int kt = 0; kt < 16; ++kt) {
    bfrag8 hi, lo; split8(whp + kt * 32, hi, lo);
    *(bfrag8*)(wb + kt * 8) = hi;
    *(bfrag8*)(wb + (16 + kt) * 8) = lo;
  }
#pragma unroll
  for (int kt = 0; kt < 8; ++kt) {
    bfrag8 hi, lo; split8(wip + kt * 32, hi, lo);
    *(bfrag8*)(wb + (32 + kt) * 8) = hi;
    *(bfrag8*)(wb + (40 + kt) * 8) = lo;
  }
  if (lane < 16) {
    int g2 = lane >> 2, u2 = lane & 3, gu2 = wg * 4 + u2;
    const float* bh = (g2 == 0) ? bhr : (g2 == 1) ? bhf : (g2 == 2) ? bhg : bho;
    const float* bi = (g2 == 0) ? bir : (g2 == 1) ? bif : (g2 == 2) ? big_ : bio;
    bias_s[wg * 16 + lane] = bh[gu2] + bi[gu2];
  }
}

// ---------------- one LSTM timestep; sync = kernel boundary (HSA-coherent) ----
// WG g: units [g*4,g*4+4) x 4 gates = 16 cols; wave w: batch tile [16w,16w+16).
// No fences / flags / atomics: stores of kernel t are visible to kernel t+1 by
// dispatch-ordered kernel-boundary coherence. h packed u32 = hi<<16 | lo.
__global__ __launch_bounds__(256, 1) void lstm_step(
    const int t,
    const int* __restrict__ words,
    const float* __restrict__ emb,
    const u16* __restrict__ wbuf,
    const float* __restrict__ bias_s,
    u32* __restrict__ hbuf,     // [2][B][H] packed hi|lo
    float* __restrict__ cbuf,   // [B][H] fp32 cell state
    u16* __restrict__ hs_all,   // [T][B][H] bf16 (attention path)
    float* __restrict__ hlast)  // [B][H] fp32 final h
{
  const int wg = blockIdx.x;
  const int tid = threadIdx.x;
  const int lane = tid & 63;
  const int wave = tid >> 6;
  const int mbase = wave * 16;
  const int colq = lane & 15;
  const int koff = (lane >> 4) * 8;
  const int arow = mbase + colq;            // batch row for A fragments

  __shared__ float gatesLds[NB * 17];       // per-wave rows; intra-wave only

  // ---- emb gather first: longest dependent chain (words -> emb row) ----
  bool is64 = ((words[1] | words[3] | words[5] | words[7]) == 0);
  int widx = arow * NT + (t - 1);
  int w = is64 ? words[2 * widx] : words[widx];
  const float* xs = emb + (size_t)w * NE + koff;
  f32x4 xa[8], xb[8];
#pragma unroll
  for (int kt = 0; kt < 8; ++kt) {
    xa[kt] = *(const f32x4*)(xs + kt * 32);
    xb[kt] = *(const f32x4*)(xs + kt * 32 + 4);
  }

  // ---- h_{t-1} loads: plain cacheable dwordx4 (kernel-boundary coherent) ----
  uint4 hq0[16], hq1[16];
  if (t > 1) {
    const u32* hp = hbuf + ((size_t)((t - 1) & 1) * NB + arow) * NH + koff;
#pragma unroll
    for (int kt = 0; kt < 16; ++kt) {
      hq0[kt] = *(const uint4*)(hp + kt * 32);
      hq1[kt] = *(const uint4*)(hp + kt * 32 + 4);
    }
  }

  const u16* wb = wbuf + (size_t)(wg * 64 + lane) * 48 * 8;
  f32x4 acc = {0.f, 0.f, 0.f, 0.f};

  // ---- h MFMAs (hi/lo 3-term, fp32-equivalent) ----
  if (t > 1) {
#pragma unroll
    for (int kt = 0; kt < 16; ++kt) {
      bfrag8 ah, al;
      uint4 q0 = hq0[kt], q1 = hq1[kt];
      ah[0] = (short)(q0.x >> 16); al[0] = (short)(q0.x & 0xffffu);
      ah[1] = (short)(q0.y >> 16); al[1] = (short)(q0.y & 0xffffu);
      ah[2] = (short)(q0.z >> 16); al[2] = (short)(q0.z & 0xffffu);
      ah[3] = (short)(q0.w >> 16); al[3] = (short)(q0.w & 0xffffu);
      ah[4] = (short)(q1.x >> 16); al[4] = (short)(q1.x & 0xffffu);
      ah[5] = (short)(q1.y >> 16); al[5] = (short)(q1.y & 0xffffu);
      ah[6] = (short)(q1.z >> 16); al[6] = (short)(q1.z & 0xffffu);
      ah[7] = (short)(q1.w >> 16); al[7] = (short)(q1.w & 0xffffu);
      bfrag8 whh = *(const bfrag8*)(wb + kt * 8);
      bfrag8 whl = *(const bfrag8*)(wb + (16 + kt) * 8);
      acc = __builtin_amdgcn_mfma_f32_16x16x32_bf16(ah, whh, acc, 0, 0, 0);
      acc = __builtin_amdgcn_mfma_f32_16x16x32_bf16(al, whh, acc, 0, 0, 0);
      acc = __builtin_amdgcn_mfma_f32_16x16x32_bf16(ah, whl, acc, 0, 0, 0);
    }
  }

  // ---- X MFMAs (emb split on the fly) ----
#pragma unroll
  for (int kt = 0; kt < 8; ++kt) {
    bfrag8 xh, xl;
#pragma unroll
    for (int i = 0; i < 4; ++i) {
      u16 h, l;
      split1(xa[kt][i], h, l); xh[i] = (short)h; xl[i] = (short)l;
      split1(xb[kt][i], h, l); xh[4 + i] = (short)h; xl[4 + i] = (short)l;
    }
    bfrag8 wih = *(const bfrag8*)(wb + (32 + kt) * 8);
    bfrag8 wil = *(const bfrag8*)(wb + (40 + kt) * 8);
    acc = __builtin_amdgcn_mfma_f32_16x16x32_bf16(xh, wih, acc, 0, 0, 0);
    acc = __builtin_amdgcn_mfma_f32_16x16x32_bf16(xl, wih, acc, 0, 0, 0);
    acc = __builtin_amdgcn_mfma_f32_16x16x32_bf16(xh, wil, acc, 0, 0, 0);
  }

  // ---- intra-wave transpose via LDS (wave's own rows; no barrier needed) ----
  {
    int drow = mbase + ((lane >> 4) << 2);
#pragma unroll
    for (int r = 0; r < 4; ++r) gatesLds[(drow + r) * 17 + colq] = acc[r];
  }

  // ---- gate math; thread owns one (b,u) in its own wave's rows ----
  {
    int b = tid >> 2, u = tid & 3;
    const float* gl = &gatesLds[b * 17];
    const float* bs = bias_s + wg * 16;
    float xr = gl[u]      + bs[u];
    float xf = gl[4 + u]  + bs[4 + u];
    float xg = gl[8 + u]  + bs[8 + u];
    float xo = gl[12 + u] + bs[12 + u];
    float rg = fsigm(xr), fg = fsigm(xf), gg = ftanh(xg), og = fsigm(xo);
    int ci = b * NH + wg * 4 + u;
    float cprev = (t > 1) ? cbuf[ci] : 0.0f;
    float cn = fg * cprev + rg * gg;
    cbuf[ci] = cn;
    float hv = og * ftanh(cn);
    u16 hhi, hlo; split1(hv, hhi, hlo);
    hbuf[((size_t)(t & 1) * NB + b) * NH + wg * 4 + u] = ((u32)hhi << 16) | (u32)hlo;
    hs_all[(size_t)(t - 1) * (NB * NH) + ci] = hhi;
    if (t == NT) hlast[ci] = hv;
  }
}

// ---------------- attention + output head (one WG per batch) ----------------
__global__ __launch_bounds__(256) void post_kernel(
    const float* __restrict__ hlast,  // [B][H] fp32
    const u16* __restrict__ hs,       // [T][B][H] bf16
    const float* __restrict__ W_ol, const float* __restrict__ b_ol,   // [256][512], [256]
    const float* __restrict__ W_att, const float* __restrict__ b_att, // [256][512], [512]
    const float* __restrict__ W_fc, const float* __restrict__ b_fc,   // [2][768], [2]
    float* __restrict__ out)          // [64*2] ++ [64*512] fp32
{
  int b = blockIdx.x, tid = threadIdx.x;
  __shared__ float hl[NH], fh[256], sc[NH], att[NT], ao[NH], red[256];

  for (int i = tid; i < NH; i += 256) {
    float hv = hlast[b * NH + i];
    hl[i] = hv;
    out[128 + b * NH + i] = hv;   // output 1: h_last
  }
  __syncthreads();

  // final_hidden[j] = b_ol[j] + hl . W_ol[j][:]
  {
    float s = b_ol[tid];
    const float* w = W_ol + (size_t)tid * NH;
    for (int k = 0; k < NH; k += 4) {
      f32x4 q = *(const f32x4*)(w + k);
      s += q[0] * hl[k] + q[1] * hl[k + 1] + q[2] * hl[k + 2] + q[3] * hl[k + 3];
    }
    fh[tid] = s;
  }
  __syncthreads();

  // score[h] = b_att[h] + sum_j fh[j] * W_att[j][h]
  for (int h = tid; h < NH; h += 256) {
    float s = b_att[h];
    for (int j = 0; j < 256; ++j) s += fh[j] * W_att[(size_t)j * NH + h];
    sc[h] = s;
  }
  __syncthreads();

  // att[t] = score . hs[t][b][:]
  for (int t = tid; t < NT; t += 256) {
    const u16* row = hs + ((size_t)t * NB + b) * NH;
    float s = 0.f;
    for (int k = 0; k < NH; k += 8) {
      uint4 q = *(const uint4*)(row + k);
      float tmp[8]; unpack8(q, tmp);
#pragma unroll
      for (int j = 0; j < 8; ++j) s += tmp[j] * sc[k + j];
    }
    att[t] = s;
  }
  __syncthreads();

  // softmax over T
  float l0 = att[tid], l1 = att[tid + 256];
  red[tid] = fmaxf(l0, l1);
  __syncthreads();
  for (int s = 128; s > 0; s >>= 1) { if (tid < s) red[tid] = fmaxf(red[tid], red[tid + s]); __syncthreads(); }
  float mx = red[0];
  __syncthreads();
  float e0 = __expf(l0 - mx), e1 = __expf(l1 - mx);
  red[tid] = e0 + e1;
  __syncthreads();
  for (int s = 128; s > 0; s >>= 1) { if (tid < s) red[tid] += red[tid + s]; __syncthreads(); }
  float inv = 1.0f / red[0];
  __syncthreads();
  att[tid] = e0 * inv;
  att[tid + 256] = e1 * inv;
  __syncthreads();

  // att_out[h] = sum_t dist[t] * hs[t][b][h]
  {
    float a0 = 0.f, a1 = 0.f;
    for (int t = 0; t < NT; ++t) {
      float d = att[t];
      const u16* row = hs + ((size_t)t * NB + b) * NH;
      a0 += d * bf2f(row[tid]);
      a1 += d * bf2f(row[tid + 256]);
    }
    ao[tid] = a0;
    ao[tid + 256] = a1;
  }
  __syncthreads();

  // out[o] = sigmoid(b_fc[o] + [fh, ao] . W_fc[o][:])
#pragma unroll
  for (int o = 0; o < 2; ++o) {
    float part = 0.f;
    for (int i = tid; i < 768; i += 256) {
      float v = (i < 256) ? fh[i] : ao[i - 256];
      part += v * W_fc[o * 768 + i];
    }
    red[tid] = part;
    __syncthreads();
    for (int s = 128; s > 0; s >>= 1) { if (tid < s) red[tid] += red[tid + s]; __syncthreads(); }
    if (tid == 0) out[b * 2 + o] = fsigm(red[0] + b_fc[o]);
    __syncthreads();
  }
}

// ---------------- host launch: 1 staging + 512 step kernels + post ----------
extern "C" void kernel_launch(void* const* d_in, const int* in_sizes, int n_in,
                              void* d_out, int out_size, void* d_ws, size_t ws_size,
                              hipStream_t stream) {
  const int* words  = (const int*)d_in[0];
  const float* emb  = (const float*)d_in[1];
  const float* Wir  = (const float*)d_in[2];  const float* bir = (const float*)d_in[3];
  const float* Whr  = (const float*)d_in[4];  const float* bhr = (const float*)d_in[5];
  const float* Wif  = (const float*)d_in[6];  const float* bif = (const float*)d_in[7];
  const float* Whf  = (const float*)d_in[8];  const float* bhf = (const float*)d_in[9];
  const float* Wig  = (const float*)d_in[10]; const float* big_ = (const float*)d_in[11];
  const float* Whg  = (const float*)d_in[12]; const float* bhg = (const float*)d_in[13];
  const float* Wio  = (const float*)d_in[14]; const float* bio = (const float*)d_in[15];
  const float* Who  = (const float*)d_in[16]; const float* bho = (const float*)d_in[17];
  const float* W_att = (const float*)d_in[18]; const float* b_att = (const float*)d_in[19];
  const float* W_ol  = (const float*)d_in[20]; const float* b_ol  = (const float*)d_in[21];
  const float* W_fc  = (const float*)d_in[22]; const float* b_fc  = (const float*)d_in[23];

  uint8_t* ws = (uint8_t*)d_ws;
  u16* hs       = (u16*)ws;                              // 512*64*512*2 = 32 MiB
  size_t off    = (size_t)33554432;
  u16* wbuf     = (u16*)(ws + off);   off += 6291456;    // 128*64*48*16B = 6 MiB
  float* bias_s = (float*)(ws + off); off += 8192;       // 128*16*4
  u32* hbuf     = (u32*)(ws + off);   off += 262144;     // 2*64*512*4
  float* cbuf   = (float*)(ws + off); off += 131072;     // 64*512*4
  float* hlast  = (float*)(ws + off);                    // 64*512*4

  stage_weights<<<dim3(NWG), dim3(64), 0, stream>>>(
      Whr, Whf, Whg, Who, Wir, Wif, Wig, Wio,
      bhr, bhf, bhg, bho, bir, bif, big_, bio, wbuf, bias_s);

  for (int t = 1; t <= NT; ++t) {
    lstm_step<<<dim3(NWG), dim3(256), 0, stream>>>(
        t, words, emb, wbuf, bias_s, hbuf, cbuf, hs, hlast);
  }

  post_kernel<<<dim3(NB), dim3(256), 0, stream>>>(hlast, hs, W_ol, b_ol, W_att, b_att,
                                                  W_fc, b_fc, (float*)d_out);
}